// Round 9
// baseline (134.252 us; speedup 1.0000x reference)
//
#include <hip/hip_runtime.h>
#include <math.h>

#define KC 8
#define DD 16
#define BLK 256

typedef short short8 __attribute__((ext_vector_type(8)));    // 8 bf16 (4 VGPRs)
typedef float floatx16 __attribute__((ext_vector_type(16))); // 32x32 MFMA acc

__device__ __forceinline__ unsigned asu(float x) { return __float_as_uint(x); }

// ---------------------------------------------------------------------------
// FUSED kernel, R9: R8 failed post-timing (first launch right, replays wrong)
// with prep guarded by `if (tid < 128)` — suspect exec-masked shuffle region
// around block barriers. Fix: NO divergence — all 256 threads run prep, with
// waves 2-3 bit-exactly duplicating waves 0-1's components (duplicate stores
// of identical bytes are benign). Data loads moved after prep (no cross-phase
// register liveness). Phase 2 is byte-identical to R7's passing MFMA body,
// reading fragments from LDS instead of global.
// ---------------------------------------------------------------------------
__global__ __launch_bounds__(BLK, 4) void gmm_fused(
    const float* __restrict__ data,
    const float* __restrict__ logits,
    const float* __restrict__ means,
    const float* __restrict__ scales,
    float* __restrict__ out, int N)
{
    __shared__ float Ash[KC][DD][DD + 1];        // 8704 B transpose scratch
    __shared__ uint4 sAH[4 * 64];                // 4096 B A-frag hi
    __shared__ uint4 sAL[4 * 64];                // 4096 B A-frag lo
    __shared__ __align__(16) float sBF[128];     // 512 B  -b acc-init (C-layout)
    __shared__ float sC[KC];                     // 32 B   per-comp constant

    const int tid  = threadIdx.x;
    const int lane = tid & 63;
    const int half = lane >> 5;
    const int wbase = blockIdx.x * BLK + (tid & ~63);

    // ================= phase 1: prep, ALL threads (no divergence) ==========
    // waves 0-1 cover comps 0-7; waves 2-3 duplicate them bit-exactly.
    const int k    = (tid >> 4) & 7;
    const int i    = tid & 15;
    const int base = lane & 48;       // in-wave lane of this comp's row 0

    float xc[DD];
    float hld = 0.f;
    {
        // S row i of comp k -> registers
        float srow[DD];
        {
            const float4* sp = (const float4*)(scales + (size_t)(k * DD + i) * DD);
#pragma unroll
            for (int q = 0; q < 4; ++q) {
                float4 v = sp[q];
                srow[4 * q + 0] = v.x; srow[4 * q + 1] = v.y;
                srow[4 * q + 2] = v.z; srow[4 * q + 3] = v.w;
            }
        }

        // cov row i via shfl
        float a[DD];
#pragma unroll
        for (int j = 0; j < DD; ++j) a[j] = 0.f;
#pragma unroll
        for (int d = 0; d < DD; ++d) {
            float sid = srow[d];
#pragma unroll
            for (int j = 0; j < DD; ++j) {
                float sjd = __shfl(srow[d], base + j, 64);
                a[j] = fmaf(sid, sjd, a[j]);
            }
        }

        // right-looking Cholesky in registers
        float l[DD];
#pragma unroll
        for (int j = 0; j < DD; ++j) {
            float ajj = __shfl(a[j], base + j, 64);
            float ljj = sqrtf(ajj);
            hld += logf(ljj);
            float lij = (i < j) ? 0.f : (a[j] / ljj);
            l[j] = lij;
#pragma unroll
            for (int c = j + 1; c < DD; ++c) {
                float lcj = __shfl(l[j], base + c, 64);
                a[c] = fmaf(-lij, lcj, a[c]);
            }
        }

        // invert L: thread (k,i) -> column i of A = L^{-1}
#pragma unroll
        for (int r = 0; r < DD; ++r) {
            float s = (r == i) ? 1.f : 0.f;
#pragma unroll
            for (int t = 0; t < DD; ++t) {
                if (t < r) {
                    float lrt = __shfl(l[t], base + r, 64);
                    s = fmaf(-lrt, xc[t], s);
                }
            }
            float lrr = __shfl(l[r], base + r, 64);
            xc[r] = (r < i) ? 0.f : (s / lrr);
        }
    }

    // transpose columns->rows via LDS (duplicate writers write same bytes)
#pragma unroll
    for (int r = 0; r < DD; ++r) Ash[k][r][i] = xc[r];
    __syncthreads();

    {
        // row i of A + b_i
        float rowA[DD];
        float bb = 0.f;
#pragma unroll
        for (int j = 0; j < DD; ++j) {
            float aij = Ash[k][i][j];
            rowA[j] = aij;
            bb = fmaf(aij, means[k * DD + j], bb);
        }

        // emit A-fragments: pair P=k>>1, row m=(k&1)*16+i; split trunc+resid
        const int P = k >> 1;
        const int m = (k & 1) * 16 + i;
#pragma unroll
        for (int h = 0; h < 2; ++h) {
            unsigned dh[4], dl[4];
#pragma unroll
            for (int jj = 0; jj < 4; ++jj) {
                float e = rowA[h * 8 + 2 * jj];
                float o = rowA[h * 8 + 2 * jj + 1];
                unsigned he = asu(e) & 0xFFFF0000u, ho = asu(o) & 0xFFFF0000u;
                float re = e - __uint_as_float(he);
                float ro = o - __uint_as_float(ho);
                dh[jj] = (he >> 16) | ho;
                dl[jj] = ((asu(re) & 0xFFFF0000u) >> 16) | (asu(ro) & 0xFFFF0000u);
            }
            sAH[P * 64 + h * 32 + m] = make_uint4(dh[0], dh[1], dh[2], dh[3]);
            sAL[P * 64 + h * 32 + m] = make_uint4(dl[0], dl[1], dl[2], dl[3]);
        }

        // -b into 32x32 C-layout acc-init slot (bijective m -> (h,t))
        {
            const int h = (m >> 2) & 1;
            const int t = (m & 3) | ((m >> 3) << 2);
            sBF[P * 32 + h * 16 + t] = -bb;
        }

        if (i == 0) {   // 2 duplicate writers per sC[k], same value
            float mxl = logits[0];
            for (int t = 1; t < KC; ++t) mxl = fmaxf(mxl, logits[t]);
            float se = 0.f;
            for (int t = 0; t < KC; ++t) se += expf(logits[t] - mxl);
            float lse = mxl + logf(se);
            const float log2pi = 1.8378770664093453f;
            sC[k] = (logits[k] - lse) - hld - 0.5f * DD * log2pi;
        }
    }
    __syncthreads();

    // ================= phase 2: MFMA point pipeline (R7-identical) =========
    short8 bh[2], bl[2];
#pragma unroll
    for (int s = 0; s < 2; ++s) {
        int p = wbase + s * 32 + (lane & 31);
        p = p < N ? p : N - 1;
        const float4* xp = (const float4*)(data + (size_t)p * DD + half * 8);
        float4 v0 = xp[0], v1 = xp[1];
        float xs[8] = {v0.x, v0.y, v0.z, v0.w, v1.x, v1.y, v1.z, v1.w};
        unsigned dh[4], dl[4];
#pragma unroll
        for (int jj = 0; jj < 4; ++jj) {
            float e = xs[2 * jj], o = xs[2 * jj + 1];
            unsigned he = asu(e) & 0xFFFF0000u, ho = asu(o) & 0xFFFF0000u;
            float re = e - __uint_as_float(he);
            float ro = o - __uint_as_float(ho);
            dh[jj] = __builtin_amdgcn_perm(ho, he, 0x07060302u);
            dl[jj] = __builtin_amdgcn_perm(asu(ro), asu(re), 0x07060302u);
        }
        bh[s] = __builtin_bit_cast(short8, make_uint4(dh[0], dh[1], dh[2], dh[3]));
        bl[s] = __builtin_bit_cast(short8, make_uint4(dl[0], dl[1], dl[2], dl[3]));
    }

    float mx = -1e30f, sum = 0.f;

#pragma unroll 1
    for (int P = 0; P < 4; ++P) {
        short8 ah = __builtin_bit_cast(short8, sAH[P * 64 + lane]);
        short8 al = __builtin_bit_cast(short8, sAL[P * 64 + lane]);
        const float4* bfp = (const float4*)(sBF + P * 32 + half * 16);
        float4 b0 = bfp[0], b1 = bfp[1], b2 = bfp[2], b3 = bfp[3];
        float ck0 = sC[2 * P], ck1 = sC[2 * P + 1];

        float me[2], mo[2];
#pragma unroll
        for (int s = 0; s < 2; ++s) {
            floatx16 acc = {b0.x, b0.y, b0.z, b0.w, b1.x, b1.y, b1.z, b1.w,
                            b2.x, b2.y, b2.z, b2.w, b3.x, b3.y, b3.z, b3.w};
            acc = __builtin_amdgcn_mfma_f32_32x32x16_bf16(ah, bh[s], acc, 0, 0, 0);
            acc = __builtin_amdgcn_mfma_f32_32x32x16_bf16(ah, bl[s], acc, 0, 0, 0);
            acc = __builtin_amdgcn_mfma_f32_32x32x16_bf16(al, bh[s], acc, 0, 0, 0);
            float se = acc[0] * acc[0], so = acc[8] * acc[8];
#pragma unroll
            for (int t = 1; t < 8; ++t) {
                se = fmaf(acc[t], acc[t], se);
                so = fmaf(acc[t + 8], acc[t + 8], so);
            }
            me[s] = se + __shfl_xor(se, 32, 64);   // maha, comp 2P
            mo[s] = so + __shfl_xor(so, 32, 64);   // maha, comp 2P+1
        }

        float mE = half ? me[1] : me[0];
        float mO = half ? mo[1] : mo[0];

        float lpk = fmaf(-0.5f, mE, ck0);
        float nm = fmaxf(mx, lpk);
        sum = sum * __expf(mx - nm) + __expf(lpk - nm);
        mx = nm;

        lpk = fmaf(-0.5f, mO, ck1);
        nm = fmaxf(mx, lpk);
        sum = sum * __expf(mx - nm) + __expf(lpk - nm);
        mx = nm;
    }

    const int id = wbase + lane;
    if (id < N) out[id] = mx + __logf(sum);
}

extern "C" void kernel_launch(void* const* d_in, const int* in_sizes, int n_in,
                              void* d_out, int out_size, void* d_ws, size_t ws_size,
                              hipStream_t stream) {
    const float* data   = (const float*)d_in[0];
    const float* logits = (const float*)d_in[1];
    const float* means  = (const float*)d_in[2];
    const float* scales = (const float*)d_in[3];
    float* out = (float*)d_out;
    const int N = in_sizes[0] / DD;

    const int nblk = (N + BLK - 1) / BLK;
    gmm_fused<<<nblk, BLK, 0, stream>>>(data, logits, means, scales, out, N);
}

// Round 10
// 91.562 us; speedup vs baseline: 1.4662x; 1.4662x over previous
//
#include <hip/hip_runtime.h>
#include <math.h>

#define KC 8
#define DD 16
#define BLK 256

typedef short short8 __attribute__((ext_vector_type(8)));    // 8 bf16 (4 VGPRs)
typedef float floatx16 __attribute__((ext_vector_type(16))); // 32x32 MFMA acc

__device__ __forceinline__ unsigned asu(float x) { return __float_as_uint(x); }

// ---------------------------------------------------------------------------
// Kernel 1: prep (R7, passing): shuffle Cholesky + inversion, emits
//  - AH2/AL2: A-fragments of [L^-1_{2P}; L^-1_{2P+1}] (32x16), bf16 hi/lo
//  - BF: -b in 32x32 C-layout (acc-init)
//  - Cout: log mix weight - sum log L_ii - D/2 log2pi
// ---------------------------------------------------------------------------
__global__ __launch_bounds__(128) void gmm_prep(
    const float* __restrict__ logits,
    const float* __restrict__ means,
    const float* __restrict__ scales,
    uint4* __restrict__ AH2,    // [4 pairs][64 lanes]
    uint4* __restrict__ AL2,    // [4 pairs][64 lanes]
    float* __restrict__ BF,     // [4 pairs][2 halves][16]
    float* __restrict__ Cout)   // [KC]
{
    const int tid  = threadIdx.x;
    const int k    = tid >> 4;
    const int i    = tid & 15;
    const int lane = tid & 63;
    const int base = lane & 48;

    float srow[DD];
    {
        const float4* sp = (const float4*)(scales + (size_t)(k * DD + i) * DD);
#pragma unroll
        for (int q = 0; q < 4; ++q) {
            float4 v = sp[q];
            srow[4 * q + 0] = v.x; srow[4 * q + 1] = v.y;
            srow[4 * q + 2] = v.z; srow[4 * q + 3] = v.w;
        }
    }

    float a[DD];
#pragma unroll
    for (int j = 0; j < DD; ++j) a[j] = 0.f;
#pragma unroll
    for (int d = 0; d < DD; ++d) {
        float sid = srow[d];
#pragma unroll
        for (int j = 0; j < DD; ++j) {
            float sjd = __shfl(srow[d], base + j, 64);
            a[j] = fmaf(sid, sjd, a[j]);
        }
    }

    float l[DD];
    float hld = 0.f;
#pragma unroll
    for (int j = 0; j < DD; ++j) {
        float ajj = __shfl(a[j], base + j, 64);
        float ljj = sqrtf(ajj);
        hld += logf(ljj);
        float lij = (i < j) ? 0.f : (a[j] / ljj);
        l[j] = lij;
#pragma unroll
        for (int c = j + 1; c < DD; ++c) {
            float lcj = __shfl(l[j], base + c, 64);
            a[c] = fmaf(-lij, lcj, a[c]);
        }
    }

    float xc[DD];
#pragma unroll
    for (int r = 0; r < DD; ++r) {
        float s = (r == i) ? 1.f : 0.f;
#pragma unroll
        for (int t = 0; t < DD; ++t) {
            if (t < r) {
                float lrt = __shfl(l[t], base + r, 64);
                s = fmaf(-lrt, xc[t], s);
            }
        }
        float lrr = __shfl(l[r], base + r, 64);
        xc[r] = (r < i) ? 0.f : (s / lrr);
    }

    __shared__ float Ash[KC][DD][DD + 1];
#pragma unroll
    for (int r = 0; r < DD; ++r) Ash[k][r][i] = xc[r];
    __syncthreads();

    float rowA[DD];
    float bb = 0.f;
#pragma unroll
    for (int j = 0; j < DD; ++j) {
        float aij = Ash[k][i][j];
        rowA[j] = aij;
        bb = fmaf(aij, means[k * DD + j], bb);
    }

    const int P = k >> 1;
    const int m = (k & 1) * 16 + i;
#pragma unroll
    for (int h = 0; h < 2; ++h) {
        unsigned dh[4], dl[4];
#pragma unroll
        for (int jj = 0; jj < 4; ++jj) {
            float e = rowA[h * 8 + 2 * jj];
            float o = rowA[h * 8 + 2 * jj + 1];
            unsigned he = asu(e) & 0xFFFF0000u, ho = asu(o) & 0xFFFF0000u;
            float re = e - __uint_as_float(he);
            float ro = o - __uint_as_float(ho);
            dh[jj] = (he >> 16) | ho;
            dl[jj] = ((asu(re) & 0xFFFF0000u) >> 16) | (asu(ro) & 0xFFFF0000u);
        }
        AH2[P * 64 + h * 32 + m] = make_uint4(dh[0], dh[1], dh[2], dh[3]);
        AL2[P * 64 + h * 32 + m] = make_uint4(dl[0], dl[1], dl[2], dl[3]);
    }

    {
        const int h = (m >> 2) & 1;
        const int t = (m & 3) | ((m >> 3) << 2);
        BF[P * 32 + h * 16 + t] = -bb;
    }

    if (i == 0) {
        float mx = logits[0];
        for (int t = 1; t < KC; ++t) mx = fmaxf(mx, logits[t]);
        float se = 0.f;
        for (int t = 0; t < KC; ++t) se += expf(logits[t] - mx);
        float lse = mx + logf(se);
        const float log2pi = 1.8378770664093453f;
        Cout[k] = (logits[k] - lse) - hld - 0.5f * DD * log2pi;
    }
}

// ---------------------------------------------------------------------------
// Kernel 2 (R10): R7 MFMA body with two latency fixes:
//  (a) ALL A-fragments (AH/AL, 4 pairs) + Cg hoisted before the comp loop --
//      L2 latency paid once, not per iteration (~32 extra VGPRs, ~100 total).
//  (b) P-loop FULLY unrolled -> 4 independent MFMA->square->shfl->exp chains
//      interleave (R7 forced unroll 1, serializing them).
// ---------------------------------------------------------------------------
__global__ __launch_bounds__(BLK, 4) void gmm_lp(
    const float* __restrict__ data,
    const uint4* __restrict__ AH2,
    const uint4* __restrict__ AL2,
    const float* __restrict__ BF,
    const float* __restrict__ Cg,
    float* __restrict__ out, int N)
{
    const int tid  = threadIdx.x;
    const int lane = tid & 63;
    const int half = lane >> 5;
    const int wbase = blockIdx.x * BLK + (tid & ~63);

    // ---- hoisted operand loads (issue first, all independent) ----
    short8 ah[4], al[4];
#pragma unroll
    for (int P = 0; P < 4; ++P) {
        ah[P] = __builtin_bit_cast(short8, AH2[P * 64 + lane]);
        al[P] = __builtin_bit_cast(short8, AL2[P * 64 + lane]);
    }
    float ck[KC];
#pragma unroll
    for (int k = 0; k < KC; ++k) ck[k] = Cg[k];   // uniform -> scalar loads

    // ---- data load + bf16 hi/lo split (B-fragment layout by construction) --
    short8 bh[2], bl[2];
#pragma unroll
    for (int s = 0; s < 2; ++s) {
        int p = wbase + s * 32 + (lane & 31);
        p = p < N ? p : N - 1;
        const float4* xp = (const float4*)(data + (size_t)p * DD + half * 8);
        float4 v0 = xp[0], v1 = xp[1];
        float xs[8] = {v0.x, v0.y, v0.z, v0.w, v1.x, v1.y, v1.z, v1.w};
        unsigned dh[4], dl[4];
#pragma unroll
        for (int jj = 0; jj < 4; ++jj) {
            float e = xs[2 * jj], o = xs[2 * jj + 1];
            unsigned he = asu(e) & 0xFFFF0000u, ho = asu(o) & 0xFFFF0000u;
            float re = e - __uint_as_float(he);
            float ro = o - __uint_as_float(ho);
            dh[jj] = __builtin_amdgcn_perm(ho, he, 0x07060302u);
            dl[jj] = __builtin_amdgcn_perm(asu(ro), asu(re), 0x07060302u);
        }
        bh[s] = __builtin_bit_cast(short8, make_uint4(dh[0], dh[1], dh[2], dh[3]));
        bl[s] = __builtin_bit_cast(short8, make_uint4(dl[0], dl[1], dl[2], dl[3]));
    }

    float mx = -1e30f, sum = 0.f;

#pragma unroll
    for (int P = 0; P < 4; ++P) {
        const float4* bfp = (const float4*)(BF + P * 32 + half * 16);
        float4 b0 = bfp[0], b1 = bfp[1], b2 = bfp[2], b3 = bfp[3];

        float me[2], mo[2];
#pragma unroll
        for (int s = 0; s < 2; ++s) {
            floatx16 acc = {b0.x, b0.y, b0.z, b0.w, b1.x, b1.y, b1.z, b1.w,
                            b2.x, b2.y, b2.z, b2.w, b3.x, b3.y, b3.z, b3.w};
            acc = __builtin_amdgcn_mfma_f32_32x32x16_bf16(ah[P], bh[s], acc, 0, 0, 0);
            acc = __builtin_amdgcn_mfma_f32_32x32x16_bf16(ah[P], bl[s], acc, 0, 0, 0);
            acc = __builtin_amdgcn_mfma_f32_32x32x16_bf16(al[P], bh[s], acc, 0, 0, 0);
            float se = acc[0] * acc[0], so = acc[8] * acc[8];
#pragma unroll
            for (int t = 1; t < 8; ++t) {
                se = fmaf(acc[t], acc[t], se);
                so = fmaf(acc[t + 8], acc[t + 8], so);
            }
            me[s] = se + __shfl_xor(se, 32, 64);   // maha, comp 2P
            mo[s] = so + __shfl_xor(so, 32, 64);   // maha, comp 2P+1
        }

        float mE = half ? me[1] : me[0];
        float mO = half ? mo[1] : mo[0];

        float lpk = fmaf(-0.5f, mE, ck[2 * P]);
        float nm = fmaxf(mx, lpk);
        sum = sum * __expf(mx - nm) + __expf(lpk - nm);
        mx = nm;

        lpk = fmaf(-0.5f, mO, ck[2 * P + 1]);
        nm = fmaxf(mx, lpk);
        sum = sum * __expf(mx - nm) + __expf(lpk - nm);
        mx = nm;
    }

    const int id = wbase + lane;
    if (id < N) out[id] = mx + __logf(sum);
}

extern "C" void kernel_launch(void* const* d_in, const int* in_sizes, int n_in,
                              void* d_out, int out_size, void* d_ws, size_t ws_size,
                              hipStream_t stream) {
    const float* data   = (const float*)d_in[0];
    const float* logits = (const float*)d_in[1];
    const float* means  = (const float*)d_in[2];
    const float* scales = (const float*)d_in[3];
    float* out = (float*)d_out;
    const int N = in_sizes[0] / DD;

    uint4* AH2 = (uint4*)d_ws;             // 4*64 uint4 = 4 KB
    uint4* AL2 = AH2 + 4 * 64;             // 4 KB
    float* BF  = (float*)(AL2 + 4 * 64);   // 128 floats
    float* C   = BF + 128;                 // 8 floats

    gmm_prep<<<1, 128, 0, stream>>>(logits, means, scales, AH2, AL2, BF, C);
    const int nblk = (N + BLK - 1) / BLK;
    gmm_lp<<<nblk, BLK, 0, stream>>>(data, AH2, AL2, BF, C, out, N);
}